// Round 12
// baseline (167.224 us; speedup 1.0000x reference)
//
#include <hip/hip_runtime.h>
#include <hip/hip_bf16.h>

typedef __attribute__((ext_vector_type(8))) short short8;
typedef __attribute__((ext_vector_type(4))) float f32x4;

#define B_SZ 32
#define T_SZ 4096
#define H_SZ 512
#define NROWS (B_SZ * T_SZ)   // 131072
#define RB 64                 // rows per block

// packed fp32x2 -> bf16x2 (RNE)
static __device__ __forceinline__ unsigned int pack2(float a, float b) {
  unsigned int r;
  asm("v_cvt_pk_bf16_f32 %0, %1, %2" : "=v"(r) : "v"(a), "v"(b));
  return r;
}
// branch-free tanh, exact saturation: 1 - 2/(e^{2x}+1)
static __device__ __forceinline__ float fast_tanh(float x) {
  float e = __expf(2.0f * x);
  return 1.0f - 2.0f / (e + 1.0f);
}

// ---- W fp32 (512x512) -> bf16 fragments, K-CHUNK-MAJOR (same as r11) ----
// s = kc*2048 + gf*64 + kslot*16 + frow (uint4); holds W[gf*16+frow][kc*32+kslot*8..+8]
__global__ __launch_bounds__(256) void prep_w_kernel(
    const float* __restrict__ W, uint4* __restrict__ Wfrag) {
  int s = blockIdx.x * 256 + threadIdx.x;   // 0..32767
  int frow  = s & 15;
  int kslot = (s >> 4) & 3;
  int gf    = (s >> 6) & 31;
  int kc    = s >> 11;
  int g  = gf * 16 + frow;
  int k0 = kc * 32 + kslot * 8;
  const float4* Wf4 = reinterpret_cast<const float4*>(W);
  float4 lo = Wf4[g * 128 + (k0 >> 2)];
  float4 hi = Wf4[g * 128 + (k0 >> 2) + 1];
  uint4 u;
  u.x = pack2(lo.x, lo.y); u.y = pack2(lo.z, lo.w);
  u.z = pack2(hi.x, hi.y); u.w = pack2(hi.z, hi.w);
  Wfrag[s] = u;
}

// ---- fused: 64 rows x FULL N=512 per block; wave = 64 rows x 128 g ----
// acc[4 mf][8 j] f32x4 = 128 VGPR. Per K-chunk: 4 A-reads + 8 B-reads -> 32
// MFMA (1:2.67). A: 64x32 fp32->bf16 reg-staged LDS (4 KB, issue-early /
// write-late). B: 32 KB linear global_load_lds. Both double-buffered.
__global__ __launch_bounds__(256, 2) void score_fused_kernel(
    const float* __restrict__ X, const uint4* __restrict__ Wfrag,
    const float* __restrict__ v,
    float* __restrict__ num, float2* __restrict__ md) {
  __shared__ unsigned char WsA[2][4096];    // [mf(4)][lane(64)][16B]
  __shared__ unsigned char WsB[2][32768];   // [gf(32)][lane(64)][16B]
  __shared__ float sp[4][RB];
  __shared__ float pLDS[RB];

  const int tid   = threadIdx.x;
  const int lane  = tid & 63;
  const int gg    = tid >> 6;    // wave = g-group 0..3 (all waves: rows 0..63)
  const int frow  = lane & 15;
  const int kslot = lane >> 4;
  const size_t rowbase = (size_t)blockIdx.x * RB;

  // A staging: thread t -> row r=t>>2, k-octet qq=t&3 (8 k = 16 B bf16)
  const int arow = tid >> 2;
  const int aqq  = tid & 3;
  const float4* Af4 = reinterpret_cast<const float4*>(X) + (rowbase + arow) * 128 + aqq * 2;
  const int awoff = (arow >> 4) * 1024 + ((aqq * 16 + (arow & 15)) << 4);

  // B staging: 8 x 16B linear global_load_lds per thread per chunk (32 KB)
  #define STAGE_B(kc, buf)                                                      \
    {                                                                           \
      const char* src = (const char*)Wfrag + (size_t)(kc) * 32768 + tid * 16;   \
      unsigned char* dst = &WsB[buf][tid * 16];                                 \
      _Pragma("unroll")                                                         \
      for (int i = 0; i < 8; ++i)                                               \
        __builtin_amdgcn_global_load_lds((const unsigned int*)(src + i * 4096), \
                                         (unsigned int*)(dst + i * 4096), 16, 0, 0); \
    }
  #define WRITE_A(r0, r1, buf)                                                  \
    {                                                                           \
      uint4 w4;                                                                 \
      w4.x = pack2((r0).x, (r0).y); w4.y = pack2((r0).z, (r0).w);               \
      w4.z = pack2((r1).x, (r1).y); w4.w = pack2((r1).z, (r1).w);               \
      *reinterpret_cast<uint4*>(&WsA[buf][awoff]) = w4;                         \
    }

  // v-slice: vv[j] = v[(gg*8+j)*16 + frow]
  float vv[8];
  #pragma unroll
  for (int j = 0; j < 8; ++j) vv[j] = v[(gg * 8 + j) * 16 + frow];

  // prologue: chunk 0 (A loads first, then B glds; wait all, write A, barrier)
  {
    float4 x0 = Af4[0];
    float4 x1 = Af4[1];
    STAGE_B(0, 0);
    asm volatile("s_waitcnt vmcnt(0)" ::: "memory");
    WRITE_A(x0, x1, 0);
  }
  __syncthreads();

  f32x4 acc[4][8];   // [mf][j]
  #pragma unroll
  for (int m = 0; m < 4; ++m)
    #pragma unroll
    for (int j = 0; j < 8; ++j)
      acc[m][j] = (f32x4){0.f, 0.f, 0.f, 0.f};

  for (int kc = 0; kc < 16; ++kc) {
    const int buf = kc & 1;
    float4 x0, x1;
    if (kc < 15) {               // issue-early: X first (oldest), then 8 B-glds
      x0 = Af4[(kc + 1) * 8];
      x1 = Af4[(kc + 1) * 8 + 1];
      STAGE_B(kc + 1, buf ^ 1);
    }

    // A-frags (shared by all 4 waves) + B-frags (wave's g-slice)
    const unsigned char* pa = &WsA[buf][lane * 16];
    const unsigned char* pb = &WsB[buf][(gg * 8) * 1024 + lane * 16];
    short8 af0 = *reinterpret_cast<const short8*>(pa);
    short8 af1 = *reinterpret_cast<const short8*>(pa + 1024);
    short8 af2 = *reinterpret_cast<const short8*>(pa + 2048);
    short8 af3 = *reinterpret_cast<const short8*>(pa + 3072);
    #pragma unroll
    for (int j = 0; j < 8; ++j) {
      short8 bf = *reinterpret_cast<const short8*>(pb + j * 1024);
      acc[0][j] = __builtin_amdgcn_mfma_f32_16x16x32_bf16(af0, bf, acc[0][j], 0, 0, 0);
      acc[1][j] = __builtin_amdgcn_mfma_f32_16x16x32_bf16(af1, bf, acc[1][j], 0, 0, 0);
      acc[2][j] = __builtin_amdgcn_mfma_f32_16x16x32_bf16(af2, bf, acc[2][j], 0, 0, 0);
      acc[3][j] = __builtin_amdgcn_mfma_f32_16x16x32_bf16(af3, bf, acc[3][j], 0, 0, 0);
    }

    if (kc < 15) {
      // X loads are the OLDEST 2 vmem; 8 B-glds younger. Wait X only.
      asm volatile("s_waitcnt vmcnt(8)" ::: "memory");
      WRITE_A(x0, x1, buf ^ 1);
      // before next kc reads buf^1: B-glds must have landed too
      asm volatile("s_waitcnt vmcnt(0)" ::: "memory");
    }
    __syncthreads();
  }
  #undef STAGE_B
  #undef WRITE_A

  // ---- scores: row = mf*16 + kslot*4 + r; g = (gg*8+j)*16 + frow ----
  #pragma unroll
  for (int m = 0; m < 4; ++m) {
    #pragma unroll
    for (int r = 0; r < 4; ++r) {
      float s = 0.f;
      #pragma unroll
      for (int j = 0; j < 8; ++j)
        s = fmaf(vv[j], fast_tanh(acc[m][j][r]), s);
      #pragma unroll
      for (int d = 1; d < 16; d <<= 1) s += __shfl_xor(s, d);
      if (frow == 0) sp[gg][m * 16 + kslot * 4 + r] = s;
    }
  }
  __syncthreads();

  // ---- block-local softmax over RB=64 rows (single wave) ----
  if (tid < 64) {
    float s = sp[0][tid] + sp[1][tid] + sp[2][tid] + sp[3][tid];
    float m = s;
    #pragma unroll
    for (int d = 1; d < 64; d <<= 1) m = fmaxf(m, __shfl_xor(m, d));
    float p = __expf(s - m);
    pLDS[tid] = p;
    float den = p;
    #pragma unroll
    for (int d = 1; d < 64; d <<= 1) den += __shfl_xor(den, d);
    if (tid == 0) {
      float2 r2; r2.x = m; r2.y = den;
      md[blockIdx.x] = r2;
    }
  }
  __syncthreads();

  // ---- partial numerator: thread owns h = 2*tid..+1; X tile L2-hot ----
  {
    float ax = 0.f, ay = 0.f;
    const float2* xb = reinterpret_cast<const float2*>(X + rowbase * H_SZ) + tid;
    #pragma unroll 8
    for (int t = 0; t < RB; ++t) {
      float p = pLDS[t];
      float2 xv = xb[(size_t)t * (H_SZ / 2)];
      ax = fmaf(p, xv.x, ax);
      ay = fmaf(p, xv.y, ay);
    }
    float2 r; r.x = ax; r.y = ay;
    reinterpret_cast<float2*>(num + (size_t)blockIdx.x * H_SZ)[tid] = r;
  }
}

// ---- combine 64 block-partials per batch with global-max rescale ----
__global__ __launch_bounds__(512) void combine_kernel(
    const float* __restrict__ num, const float2* __restrict__ md,
    float* __restrict__ out) {
  const int b = blockIdx.x;   // 32
  const int h = threadIdx.x;  // 512
  float M = -1e30f;
  #pragma unroll 8
  for (int c = 0; c < 64; ++c) M = fmaxf(M, md[b * 64 + c].x);
  float den = 0.f, acc = 0.f;
  #pragma unroll 4
  for (int c = 0; c < 64; ++c) {
    float2 m2 = md[b * 64 + c];
    float w = __expf(m2.x - M);
    den += w * m2.y;
    acc = fmaf(w, num[(size_t)(b * 64 + c) * H_SZ + h], acc);
  }
  out[b * H_SZ + h] = acc / den;
}

extern "C" void kernel_launch(void* const* d_in, const int* in_sizes, int n_in,
                              void* d_out, int out_size, void* d_ws, size_t ws_size,
                              hipStream_t stream) {
  const float* X = (const float*)d_in[0];   // (32,4096,512)
  const float* W = (const float*)d_in[1];   // (512,512)
  const float* v = (const float*)d_in[2];   // (512,)
  float* out = (float*)d_out;               // (32,512) fp32
  unsigned char* ws = (unsigned char*)d_ws;

  uint4* Wfrag = (uint4*)(ws);                               // 512 KB
  float* num   = (float*)(ws + (512u << 10));                // 2048*512*4 = 4 MB
  float2* md   = (float2*)(ws + (512u << 10) + (4u << 20));  // 16 KB

  prep_w_kernel<<<128, 256, 0, stream>>>(W, Wfrag);
  score_fused_kernel<<<NROWS / RB, 256, 0, stream>>>(X, Wfrag, v, num, md);
  combine_kernel<<<B_SZ, 512, 0, stream>>>(num, md, out);
}

// Round 13
// 138.585 us; speedup vs baseline: 1.2067x; 1.2067x over previous
//
#include <hip/hip_runtime.h>
#include <hip/hip_bf16.h>

typedef __attribute__((ext_vector_type(8))) short short8;
typedef __attribute__((ext_vector_type(4))) float f32x4;

#define B_SZ 32
#define T_SZ 4096
#define H_SZ 512
#define NROWS (B_SZ * T_SZ)   // 131072

// packed fp32x2 -> bf16x2 (RNE)
static __device__ __forceinline__ unsigned int pack2(float a, float b) {
  unsigned int r;
  asm("v_cvt_pk_bf16_f32 %0, %1, %2" : "=v"(r) : "v"(a), "v"(b));
  return r;
}
// branch-free tanh, exact saturation: 1 - 2/(e^{2x}+1)
static __device__ __forceinline__ float fast_tanh(float x) {
  float e = __expf(2.0f * x);
  return 1.0f - 2.0f / (e + 1.0f);
}

// ---- W fp32 (512x512) -> bf16 fragments, 64g-CHUNK-MAJOR, full-K ----
// uint4 s = c*4096 + j*1024 + kt*64 + kslot*16 + frow
// holds W[g = c*64 + j*16 + frow][kt*32 + kslot*8 .. +8]
// one chunk c = 64 g x 512 k = 4096 uint4 = 64 KB contiguous, fragment-linear.
__global__ __launch_bounds__(256) void prep_w_kernel(
    const float* __restrict__ W, uint4* __restrict__ Wfrag) {
  int s = blockIdx.x * 256 + threadIdx.x;   // 0..32767
  int frow  = s & 15;
  int kslot = (s >> 4) & 3;
  int kt    = (s >> 6) & 15;
  int j     = (s >> 10) & 3;
  int c     = s >> 12;
  int g  = c * 64 + j * 16 + frow;
  int k0 = kt * 32 + kslot * 8;
  const float4* Wf4 = reinterpret_cast<const float4*>(W);
  float4 lo = Wf4[g * 128 + (k0 >> 2)];
  float4 hi = Wf4[g * 128 + (k0 >> 2) + 1];
  uint4 u;
  u.x = pack2(lo.x, lo.y); u.y = pack2(lo.z, lo.w);
  u.z = pack2(hi.x, hi.y); u.w = pack2(hi.z, hi.w);
  Wfrag[s] = u;
}

// ---- fused: scores + block softmax + partial numerator ----
// 256 thr = 4 waves, wave owns 32 rows (A full-K in regs, 128 VGPR).
// W: 8 chunks of 64 g x 512 k (64 KB LDS, single-buffered). Per chunk each
// wave runs 128 MFMAs between one barrier pair -> only 16 barriers/block;
// the per-chunk stage drain (~600 cyc) is ~12% overhead instead of ~70%.
__global__ __launch_bounds__(256, 2) void score_fused_kernel(
    const float* __restrict__ X, const uint4* __restrict__ Wfrag,
    const float* __restrict__ v,
    float* __restrict__ num, float2* __restrict__ md) {
  __shared__ unsigned char WsB[65536];   // [j(4)][kt(16)][lane(64)][16B]
  __shared__ float sLDS[128];
  __shared__ float pLDS[128];
  __shared__ float mred[2], dred[2];

  const int tid   = threadIdx.x;
  const int lane  = tid & 63;
  const int wave  = tid >> 6;
  const int frow  = lane & 15;
  const int kslot = lane >> 4;
  const size_t rowbase = (size_t)blockIdx.x * 128;

  // A fragments, 2 rowsets: X[row][kt*32 + kslot*8 .. +8], bf16-packed
  short8 afrag0[16], afrag1[16];
  {
    const float4* xr0 = reinterpret_cast<const float4*>(X + (rowbase + wave * 32 + frow) * H_SZ);
    const float4* xr1 = reinterpret_cast<const float4*>(X + (rowbase + wave * 32 + 16 + frow) * H_SZ);
    #pragma unroll
    for (int kt = 0; kt < 16; ++kt) {
      float4 lo0 = xr0[kt * 8 + kslot * 2];
      float4 hi0 = xr0[kt * 8 + kslot * 2 + 1];
      union { uint4 u; short8 s; } c0;
      c0.u.x = pack2(lo0.x, lo0.y); c0.u.y = pack2(lo0.z, lo0.w);
      c0.u.z = pack2(hi0.x, hi0.y); c0.u.w = pack2(hi0.z, hi0.w);
      afrag0[kt] = c0.s;
      float4 lo1 = xr1[kt * 8 + kslot * 2];
      float4 hi1 = xr1[kt * 8 + kslot * 2 + 1];
      union { uint4 u; short8 s; } c1;
      c1.u.x = pack2(lo1.x, lo1.y); c1.u.y = pack2(lo1.z, lo1.w);
      c1.u.z = pack2(hi1.x, hi1.y); c1.u.w = pack2(hi1.z, hi1.w);
      afrag1[kt] = c1.s;
    }
  }

  float red0[4] = {0.f, 0.f, 0.f, 0.f};
  float red1[4] = {0.f, 0.f, 0.f, 0.f};

  for (int c = 0; c < 8; ++c) {
    // stage chunk c: 64 KB linear, 16 x 16B glds per thread
    {
      const char* src = (const char*)Wfrag + (size_t)c * 65536 + tid * 16;
      unsigned char* dst = WsB + tid * 16;
      #pragma unroll
      for (int i = 0; i < 16; ++i)
        __builtin_amdgcn_global_load_lds((const unsigned int*)(src + i * 4096),
                                         (unsigned int*)(dst + i * 4096), 16, 0, 0);
    }
    // v-slice for this chunk (L1-hot; drained by the same vmcnt(0))
    float vv0 = v[c * 64 + frow];
    float vv1 = v[c * 64 + 16 + frow];
    float vv2 = v[c * 64 + 32 + frow];
    float vv3 = v[c * 64 + 48 + frow];

    asm volatile("s_waitcnt vmcnt(0)" ::: "memory");
    __builtin_amdgcn_s_barrier();
    __builtin_amdgcn_sched_barrier(0);

    f32x4 acc[2][4];   // [rowset][j]
    #pragma unroll
    for (int a = 0; a < 2; ++a)
      #pragma unroll
      for (int j = 0; j < 4; ++j)
        acc[a][j] = (f32x4){0.f, 0.f, 0.f, 0.f};

    const unsigned char* bb = WsB + lane * 16;
    __builtin_amdgcn_s_setprio(1);
    #pragma unroll
    for (int kt = 0; kt < 16; ++kt) {
      short8 b0 = *reinterpret_cast<const short8*>(bb + (0 * 16 + kt) * 1024);
      short8 b1 = *reinterpret_cast<const short8*>(bb + (1 * 16 + kt) * 1024);
      short8 b2 = *reinterpret_cast<const short8*>(bb + (2 * 16 + kt) * 1024);
      short8 b3 = *reinterpret_cast<const short8*>(bb + (3 * 16 + kt) * 1024);
      acc[0][0] = __builtin_amdgcn_mfma_f32_16x16x32_bf16(afrag0[kt], b0, acc[0][0], 0, 0, 0);
      acc[1][0] = __builtin_amdgcn_mfma_f32_16x16x32_bf16(afrag1[kt], b0, acc[1][0], 0, 0, 0);
      acc[0][1] = __builtin_amdgcn_mfma_f32_16x16x32_bf16(afrag0[kt], b1, acc[0][1], 0, 0, 0);
      acc[1][1] = __builtin_amdgcn_mfma_f32_16x16x32_bf16(afrag1[kt], b1, acc[1][1], 0, 0, 0);
      acc[0][2] = __builtin_amdgcn_mfma_f32_16x16x32_bf16(afrag0[kt], b2, acc[0][2], 0, 0, 0);
      acc[1][2] = __builtin_amdgcn_mfma_f32_16x16x32_bf16(afrag1[kt], b2, acc[1][2], 0, 0, 0);
      acc[0][3] = __builtin_amdgcn_mfma_f32_16x16x32_bf16(afrag0[kt], b3, acc[0][3], 0, 0, 0);
      acc[1][3] = __builtin_amdgcn_mfma_f32_16x16x32_bf16(afrag1[kt], b3, acc[1][3], 0, 0, 0);
    }
    __builtin_amdgcn_s_setprio(0);

    // chunk epilogue: D[m][n] n=frow within g-group j, m=kslot*4+r
    #pragma unroll
    for (int r = 0; r < 4; ++r) {
      red0[r] = fmaf(vv0, fast_tanh(acc[0][0][r]), red0[r]);
      red0[r] = fmaf(vv1, fast_tanh(acc[0][1][r]), red0[r]);
      red0[r] = fmaf(vv2, fast_tanh(acc[0][2][r]), red0[r]);
      red0[r] = fmaf(vv3, fast_tanh(acc[0][3][r]), red0[r]);
      red1[r] = fmaf(vv0, fast_tanh(acc[1][0][r]), red1[r]);
      red1[r] = fmaf(vv1, fast_tanh(acc[1][1][r]), red1[r]);
      red1[r] = fmaf(vv2, fast_tanh(acc[1][2][r]), red1[r]);
      red1[r] = fmaf(vv3, fast_tanh(acc[1][3][r]), red1[r]);
    }

    __builtin_amdgcn_s_barrier();   // all waves done reading before next stage
  }

  // reduce over the 16 g-lanes (frow) within each kslot group
  #pragma unroll
  for (int r = 0; r < 4; ++r) {
    #pragma unroll
    for (int d = 1; d < 16; d <<= 1) {
      red0[r] += __shfl_xor(red0[r], d);
      red1[r] += __shfl_xor(red1[r], d);
    }
  }
  if (frow == 0) {
    float* sp = sLDS + wave * 32 + kslot * 4;
    sp[0]  = red0[0]; sp[1]  = red0[1]; sp[2]  = red0[2]; sp[3]  = red0[3];
    sp[16] = red1[0]; sp[17] = red1[1]; sp[18] = red1[2]; sp[19] = red1[3];
  }
  __syncthreads();

  // ---- block-local softmax stats over the 128 rows ----
  if (tid < 128) {
    float s = sLDS[tid];
    float m = s;
    #pragma unroll
    for (int d = 1; d < 64; d <<= 1) m = fmaxf(m, __shfl_xor(m, d));
    if ((tid & 63) == 0) mred[tid >> 6] = m;
  }
  __syncthreads();
  const float m_loc = fmaxf(mred[0], mred[1]);
  if (tid < 128) {
    float p = __expf(sLDS[tid] - m_loc);
    pLDS[tid] = p;
    #pragma unroll
    for (int d = 1; d < 64; d <<= 1) p += __shfl_xor(p, d);
    if ((tid & 63) == 0) dred[tid >> 6] = p;
  }
  __syncthreads();

  // ---- partial numerator: thread owns h = 2*tid..+1; X tile L2/L3-hot ----
  {
    float ax = 0.f, ay = 0.f;
    const float2* xb = reinterpret_cast<const float2*>(X + rowbase * H_SZ) + tid;
    #pragma unroll 8
    for (int t = 0; t < 128; ++t) {
      float p = pLDS[t];
      float2 xv = xb[(size_t)t * (H_SZ / 2)];
      ax = fmaf(p, xv.x, ax);
      ay = fmaf(p, xv.y, ay);
    }
    float2 r; r.x = ax; r.y = ay;
    reinterpret_cast<float2*>(num + (size_t)blockIdx.x * H_SZ)[tid] = r;
  }
  if (tid == 0) {
    float2 r; r.x = m_loc; r.y = dred[0] + dred[1];
    md[blockIdx.x] = r;
  }
}

// ---- combine 32 block-partials per batch with global-max rescale ----
__global__ __launch_bounds__(512) void combine_kernel(
    const float* __restrict__ num, const float2* __restrict__ md,
    float* __restrict__ out) {
  const int b = blockIdx.x;   // 32
  const int h = threadIdx.x;  // 512
  float M = -1e30f;
  #pragma unroll
  for (int c = 0; c < 32; ++c) M = fmaxf(M, md[b * 32 + c].x);
  float den = 0.f, acc = 0.f;
  #pragma unroll 4
  for (int c = 0; c < 32; ++c) {
    float2 m2 = md[b * 32 + c];
    float w = __expf(m2.x - M);
    den += w * m2.y;
    acc = fmaf(w, num[(size_t)(b * 32 + c) * H_SZ + h], acc);
  }
  out[b * H_SZ + h] = acc / den;
}

extern "C" void kernel_launch(void* const* d_in, const int* in_sizes, int n_in,
                              void* d_out, int out_size, void* d_ws, size_t ws_size,
                              hipStream_t stream) {
  const float* X = (const float*)d_in[0];   // (32,4096,512)
  const float* W = (const float*)d_in[1];   // (512,512)
  const float* v = (const float*)d_in[2];   // (512,)
  float* out = (float*)d_out;               // (32,512) fp32
  unsigned char* ws = (unsigned char*)d_ws;

  uint4* Wfrag = (uint4*)(ws);                               // 512 KB
  float* num   = (float*)(ws + (512u << 10));                // 1024*512*4 = 2 MB
  float2* md   = (float2*)(ws + (512u << 10) + (2u << 20));  // 8 KB

  prep_w_kernel<<<128, 256, 0, stream>>>(W, Wfrag);
  score_fused_kernel<<<NROWS / 128, 256, 0, stream>>>(X, Wfrag, v, num, md);
  combine_kernel<<<B_SZ, 512, 0, stream>>>(num, md, out);
}